// Round 15
// baseline (615.792 us; speedup 1.0000x reference)
//
#include <hip/hip_runtime.h>
#include <math.h>

// ---- problem constants ----
#define NT   16384
#define HD   4096
#define NE   64
#define TOPK 8

// ---- MFMA gemm tiling (r6/r14 skeleton — produced passing logits) ----
#define BM     128
#define KSPLIT 4
#define KSLICE (HD / KSPLIT)   // 1024

// ---- d_out layout: FLOAT32 elements (proven rounds 5-13) ----
#define L_OFF 0
#define W_OFF (NT * NE)                  // 1048576
#define I_OFF (W_OFF + NT * TOPK)        // 1179648
#define M_OFF (I_OFF + NT * TOPK)        // 1310720 ; mask = 8388608 floats

// scratch inside the mask region (consumed before kz_mask zeroes it):
//   partials: M_OFF .. +4194304
//   wh/wl   : M_OFF+4194304 .. +262144 (bf16 planes, 1 MB)
//   cnt     : M_OFF+4456448 (1 int)
//   list    : M_OFF+4456449 .. 3*NT ints (refine entries {t, maskLo, maskHi})
#define P_FLOATS   (KSPLIT * NT * NE)    // 4194304
#define WHL_FLOATS (NE * HD / 2 * 2)     // 262144 floats = 1 MB (wh+wl as u16)
#define CNT_OFF    (M_OFF + P_FLOATS + WHL_FLOATS)
#define LIST_OFF   (CNT_OFF + 1)

#define THR 8e-3f                        // refine threshold (>> 2*eta ~ 8e-4)

typedef __attribute__((ext_vector_type(4))) float  f4;
typedef __attribute__((ext_vector_type(8))) short  short8;
typedef __attribute__((ext_vector_type(8))) __bf16 bf16x8;

__device__ __forceinline__ unsigned short bf16_rne(float f) {
  union { float f; unsigned u; } c; c.f = f;
  unsigned r = c.u + 0x7FFFu + ((c.u >> 16) & 1u);
  return (unsigned short)(r >> 16);
}
__device__ __forceinline__ float bf16_to_f32(unsigned short h) {
  union { unsigned u; float f; } c; c.u = ((unsigned)h) << 16;
  return c.f;
}

// ---- kernel 1: gate_w fp32 -> bf16 hi/lo planes; zero refine counter ----
__global__ __launch_bounds__(256) void k_wconv(const float* __restrict__ w,
                                               unsigned short* __restrict__ wh,
                                               unsigned short* __restrict__ wl,
                                               int* __restrict__ cnt) {
  if (blockIdx.x == 0 && threadIdx.x == 0) *cnt = 0;
  int i = blockIdx.x * 256 + threadIdx.x;       // NE*HD = 262144
  float v = w[i];
  unsigned short h = bf16_rne(v);
  wh[i] = h;
  wl[i] = bf16_rne(v - bf16_to_f32(h));         // v-hi exact (Sterbenz)
}

// ---- kernel 2: split-K MFMA GEMM, hi/lo 3-term (r14 verbatim) ----
__global__ __launch_bounds__(256) void k_gemm(const float* __restrict__ x,
                                              const unsigned short* __restrict__ wh,
                                              const unsigned short* __restrict__ wl,
                                              float* __restrict__ partial) {
  const int lane  = threadIdx.x & 63;
  const int wv    = threadIdx.x >> 6;
  const int tok0  = blockIdx.x * BM;
  const int split = blockIdx.y;
  const int kbase = split * KSLICE;

  const int row15 = lane & 15;
  const int kgrp  = lane >> 4;

  f4 acc[2][4];
#pragma unroll
  for (int m = 0; m < 2; ++m)
#pragma unroll
    for (int n = 0; n < 4; ++n) acc[m][n] = (f4){0.f, 0.f, 0.f, 0.f};

  const float* xp0 = x + (size_t)(tok0 + wv * 32 + row15) * HD + kbase + kgrp * 8;
  const float* xp1 = xp0 + (size_t)16 * HD;
  const unsigned short* whp = wh + (size_t)row15 * HD + kbase + kgrp * 8;
  const unsigned short* wlp = wl + (size_t)row15 * HD + kbase + kgrp * 8;

#pragma unroll 4
  for (int it = 0; it < KSLICE / 32; ++it) {
    const int ko = it * 32;
    bf16x8 ah[2], al[2];
#pragma unroll
    for (int m = 0; m < 2; ++m) {
      const float* xp = (m == 0) ? xp0 : xp1;
      f4 vlo = *(const f4*)(xp + ko);
      f4 vhi = *(const f4*)(xp + ko + 4);
#pragma unroll
      for (int j = 0; j < 8; ++j) {
        float v = (j < 4) ? vlo[j] : vhi[j - 4];
        __bf16 h = (__bf16)v;
        __bf16 l = (__bf16)(v - (float)h);
        ah[m][j] = h; al[m][j] = l;
      }
    }
    bf16x8 bh[4], bl[4];
#pragma unroll
    for (int n = 0; n < 4; ++n) {
      bh[n] = __builtin_bit_cast(bf16x8, *(const short8*)(whp + (size_t)n * 16 * HD + ko));
      bl[n] = __builtin_bit_cast(bf16x8, *(const short8*)(wlp + (size_t)n * 16 * HD + ko));
    }
#pragma unroll
    for (int n = 0; n < 4; ++n)
#pragma unroll
      for (int m = 0; m < 2; ++m) {
        acc[m][n] = __builtin_amdgcn_mfma_f32_16x16x32_bf16(ah[m], bh[n], acc[m][n], 0, 0, 0);
        acc[m][n] = __builtin_amdgcn_mfma_f32_16x16x32_bf16(al[m], bh[n], acc[m][n], 0, 0, 0);
        acc[m][n] = __builtin_amdgcn_mfma_f32_16x16x32_bf16(ah[m], bl[n], acc[m][n], 0, 0, 0);
      }
  }

#pragma unroll
  for (int m = 0; m < 2; ++m)
#pragma unroll
    for (int n = 0; n < 4; ++n) {
      int row = tok0 + wv * 32 + m * 16 + (lane >> 4) * 4;
      int col = n * 16 + (lane & 15);
      float* dst = partial + ((size_t)split * NT + row) * NE + col;
#pragma unroll
      for (int i = 0; i < 4; ++i) dst[(size_t)i * NE] = acc[m][n][i];
    }
}

// ---- kernel 3: reduce -> approx logits; flag tokens with tight top-9 gaps ----
__global__ __launch_bounds__(256) void k_reduce(const float* __restrict__ partial,
                                                const float* __restrict__ bias,
                                                float* __restrict__ out,
                                                int* __restrict__ cnt,
                                                int* __restrict__ list) {
  const int lane = threadIdx.x & 63;            // lane == expert
  const int wv   = threadIdx.x >> 6;
  const int t    = blockIdx.x * 4 + wv;

  float v = bias[lane];
#pragma unroll
  for (int s = 0; s < KSPLIT; ++s)
    v += partial[((size_t)s * NT + t) * NE + lane];
  out[L_OFF + (size_t)t * NE + lane] = v;       // approx logit (err << 1.26)

  // stable rank (lax.top_k order)
  int rank = 0;
  for (int e = 0; e < NE; ++e) {
    float ve = __shfl(v, e);
    rank += (ve > v) || (ve == v && e < lane);
  }

  // neighbor values in rank space (ranks 0..8 only matter)
  float up = INFINITY, dn = -INFINITY;
#pragma unroll
  for (int r = 0; r < 9; ++r) {
    unsigned long long b = __ballot(rank == r);
    int src = __ffsll((unsigned long long)b) - 1;
    float vr = __shfl(v, src);
    if (rank == r + 1) up = vr;                 // value ranked just above me
    if (rank + 1 == r) dn = vr;                 // value ranked just below me
  }
  bool flag = (rank <= 8) && ((up - v < THR) || (rank <= 7 && (v - dn) < THR));

  unsigned long long m = __ballot(flag);
  if (m != 0ull && lane == 0) {
    int slot = atomicAdd(cnt, 1);
    list[3 * slot + 0] = t;
    list[3 * slot + 1] = (int)(unsigned)(m & 0xFFFFFFFFull);
    list[3 * slot + 2] = (int)(unsigned)(m >> 32);
  }
}

// ---- kernel 4: exact round-5-chain recompute for flagged (t,e); overwrite logits ----
__global__ __launch_bounds__(64) void k_refine(const float* __restrict__ x,
                                               const float* __restrict__ w,
                                               const float* __restrict__ bias,
                                               const int* __restrict__ cnt,
                                               const int* __restrict__ list,
                                               float* __restrict__ out) {
  const int b = blockIdx.x;
  if (b >= *cnt) return;
  const int t  = list[3 * b + 0];
  const unsigned lo = (unsigned)list[3 * b + 1];
  const unsigned hi = (unsigned)list[3 * b + 2];
  const int lane = threadIdx.x;
  const bool active = (lane < 32) ? ((lo >> lane) & 1u) : ((hi >> (lane - 32)) & 1u);
  if (!active) return;

  // EXACT round-5 accumulation: 4 chains (k mod 4), k ascending, fmaf
  const f4* xp = (const f4*)(x + (size_t)t * HD);
  const f4* wp = (const f4*)(w + (size_t)lane * HD);
  f4 c = (f4){0.f, 0.f, 0.f, 0.f};
#pragma unroll 4
  for (int it = 0; it < HD / 4; ++it) {
    f4 xv = xp[it];
    f4 wv = wp[it];
    c[0] = fmaf(xv[0], wv[0], c[0]);
    c[1] = fmaf(xv[1], wv[1], c[1]);
    c[2] = fmaf(xv[2], wv[2], c[2]);
    c[3] = fmaf(xv[3], wv[3], c[3]);
  }
  out[L_OFF + (size_t)t * NE + lane] = c[0] + c[1] + c[2] + c[3] + bias[lane];
}

// ---- kernel 5: zero the fp32 mask region ----
__global__ __launch_bounds__(256) void kz_mask(f4* __restrict__ p, int n4) {
  f4 z = {0.f, 0.f, 0.f, 0.f};
  for (int i = blockIdx.x * 256 + threadIdx.x; i < n4; i += gridDim.x * 256) p[i] = z;
}

// ---- kernel 6: top-8 from logits (rounds 5-13 verbatim selection) ----
__global__ __launch_bounds__(256) void k_topk(float* __restrict__ out) {
  const int lane = threadIdx.x & 63;            // lane == expert
  const int wv   = threadIdx.x >> 6;
  const int t    = blockIdx.x * 4 + wv;

  float v = out[L_OFF + (size_t)t * NE + lane];

  int rank = 0;
  for (int e = 0; e < NE; ++e) {
    float ve = __shfl(v, e);
    rank += (ve > v) || (ve == v && e < lane);
  }

  float m0 = v;
#pragma unroll
  for (int o = 32; o; o >>= 1) m0 = fmaxf(m0, __shfl_xor(m0, o));
  float ev = (rank < TOPK) ? expf(v - m0) : 0.f;
  float s = ev;
#pragma unroll
  for (int o = 32; o; o >>= 1) s += __shfl_xor(s, o);

  if (rank < TOPK) {
    out[W_OFF + (size_t)t * TOPK + rank] = ev / s;
    out[I_OFF + (size_t)t * TOPK + rank] = (float)lane;
    out[M_OFF + ((size_t)lane * TOPK + rank) * NT + t] = 1.0f;
  }
}

extern "C" void kernel_launch(void* const* d_in, const int* in_sizes, int n_in,
                              void* d_out, int out_size, void* d_ws, size_t ws_size,
                              hipStream_t stream) {
  const float* x  = (const float*)d_in[0];
  const float* gw = (const float*)d_in[1];
  const float* gb = (const float*)d_in[2];
  float* out = (float*)d_out;

  float* partial = out + M_OFF;                             // 4.19M floats
  unsigned short* wh = (unsigned short*)(out + M_OFF + P_FLOATS);  // 1 MB hi/lo planes
  unsigned short* wl = wh + (size_t)NE * HD;
  int* cnt  = (int*)(out + CNT_OFF);
  int* list = (int*)(out + LIST_OFF);

  k_wconv <<<(NE * HD) / 256, 256, 0, stream>>>(gw, wh, wl, cnt);
  k_gemm  <<<dim3(NT / BM, KSPLIT), 256, 0, stream>>>(x, wh, wl, partial);
  k_reduce<<<NT / 4, 256, 0, stream>>>(partial, gb, out, cnt, list);
  k_refine<<<NT, 64, 0, stream>>>(x, gw, gb, cnt, list, out);
  kz_mask <<<2048, 256, 0, stream>>>((f4*)(out + M_OFF), (NE * TOPK * NT) / 4);
  k_topk  <<<NT / 4, 256, 0, stream>>>(out);
}

// Round 16
// 440.589 us; speedup vs baseline: 1.3977x; 1.3977x over previous
//
#include <hip/hip_runtime.h>
#include <math.h>

// ---- problem constants ----
#define NT   16384
#define HD   4096
#define NE   64
#define TOPK 8

// ---- MFMA gemm tiling ----
#define BM     64
#define KSPLIT 4
#define KSLICE (HD / KSPLIT)   // 1024

// ---- d_out layout: FLOAT32 elements (proven rounds 5-15) ----
#define L_OFF 0
#define W_OFF (NT * NE)                  // 1048576
#define I_OFF (W_OFF + NT * TOPK)        // 1179648
#define M_OFF (I_OFF + NT * TOPK)        // 1310720 ; mask = 8388608 floats

// scratch inside the mask region (consumed before kz_mask zeroes it):
#define P_FLOATS   (KSPLIT * NT * NE)    // 4194304 (partials)
#define WHL_FLOATS (NE * HD / 2 * 2)     // 262144 floats = 1 MB (wh+wl u16 planes)
#define CNT_OFF    (M_OFF + P_FLOATS + WHL_FLOATS)
#define PAIR_OFF   (CNT_OFF + 1)         // capacity ~3.9M pairs >= max 1M

#define THR 2.5e-3f                      // refine threshold (~12x over 2*eta_worst)

typedef __attribute__((ext_vector_type(4))) float  f4;
typedef __attribute__((ext_vector_type(8))) short  short8;
typedef __attribute__((ext_vector_type(8))) __bf16 bf16x8;

__device__ __forceinline__ unsigned short bf16_rne(float f) {
  union { float f; unsigned u; } c; c.f = f;
  unsigned r = c.u + 0x7FFFu + ((c.u >> 16) & 1u);
  return (unsigned short)(r >> 16);
}
__device__ __forceinline__ float bf16_to_f32(unsigned short h) {
  union { unsigned u; float f; } c; c.u = ((unsigned)h) << 16;
  return c.f;
}

// ---- kernel 1: gate_w fp32 -> bf16 hi/lo planes; zero refine counter ----
__global__ __launch_bounds__(256) void k_wconv(const float* __restrict__ w,
                                               unsigned short* __restrict__ wh,
                                               unsigned short* __restrict__ wl,
                                               int* __restrict__ cnt) {
  if (blockIdx.x == 0 && threadIdx.x == 0) *cnt = 0;
  int i = blockIdx.x * 256 + threadIdx.x;       // NE*HD = 262144
  float v = w[i];
  unsigned short h = bf16_rne(v);
  wh[i] = h;
  wl[i] = bf16_rne(v - bf16_to_f32(h));         // v-hi exact (Sterbenz)
}

// ---- kernel 2: split-K MFMA GEMM, hi/lo 3-term; BM=64 for 4 blocks/CU ----
__global__ __launch_bounds__(256, 4) void k_gemm(const float* __restrict__ x,
                                                 const unsigned short* __restrict__ wh,
                                                 const unsigned short* __restrict__ wl,
                                                 float* __restrict__ partial) {
  const int lane  = threadIdx.x & 63;
  const int wv    = threadIdx.x >> 6;            // 0..3 -> token rows wv*16..+15
  const int tok0  = blockIdx.x * BM;
  const int split = blockIdx.y;
  const int kbase = split * KSLICE;

  const int row15 = lane & 15;
  const int kgrp  = lane >> 4;

  f4 acc[4];
#pragma unroll
  for (int n = 0; n < 4; ++n) acc[n] = (f4){0.f, 0.f, 0.f, 0.f};

  const float* xp = x + (size_t)(tok0 + wv * 16 + row15) * HD + kbase + kgrp * 8;
  const unsigned short* whp = wh + (size_t)row15 * HD + kbase + kgrp * 8;
  const unsigned short* wlp = wl + (size_t)row15 * HD + kbase + kgrp * 8;

#pragma unroll 2
  for (int it = 0; it < KSLICE / 32; ++it) {
    const int ko = it * 32;

    // A fragment: fp32 -> bf16 hi/lo in-register
    f4 vlo = *(const f4*)(xp + ko);
    f4 vhi = *(const f4*)(xp + ko + 4);
    bf16x8 ah, al;
#pragma unroll
    for (int j = 0; j < 8; ++j) {
      float v = (j < 4) ? vlo[j] : vhi[j - 4];
      __bf16 h = (__bf16)v;
      al[j] = (__bf16)(v - (float)h);
      ah[j] = h;
    }
    // B fragments + 3-term accumulate
#pragma unroll
    for (int n = 0; n < 4; ++n) {
      bf16x8 bh = __builtin_bit_cast(bf16x8, *(const short8*)(whp + (size_t)n * 16 * HD + ko));
      bf16x8 bl = __builtin_bit_cast(bf16x8, *(const short8*)(wlp + (size_t)n * 16 * HD + ko));
      acc[n] = __builtin_amdgcn_mfma_f32_16x16x32_bf16(ah, bh, acc[n], 0, 0, 0);
      acc[n] = __builtin_amdgcn_mfma_f32_16x16x32_bf16(al, bh, acc[n], 0, 0, 0);
      acc[n] = __builtin_amdgcn_mfma_f32_16x16x32_bf16(ah, bl, acc[n], 0, 0, 0);
    }
  }

  // epilogue: C/D layout: col = lane&15, row = (lane>>4)*4 + reg
#pragma unroll
  for (int n = 0; n < 4; ++n) {
    int row = tok0 + wv * 16 + (lane >> 4) * 4;
    int col = n * 16 + (lane & 15);
    float* dst = partial + ((size_t)split * NT + row) * NE + col;
#pragma unroll
    for (int i = 0; i < 4; ++i) dst[(size_t)i * NE] = acc[n][i];
  }
}

// ---- kernel 3: reduce -> approx logits; flag tight pairs; compact (t,e) list ----
__global__ __launch_bounds__(256) void k_reduce(const float* __restrict__ partial,
                                                const float* __restrict__ bias,
                                                float* __restrict__ out,
                                                int* __restrict__ cnt,
                                                int* __restrict__ pairs) {
  const int lane = threadIdx.x & 63;            // lane == expert
  const int wvi  = threadIdx.x >> 6;
  const int t    = blockIdx.x * 4 + wvi;

  float v = bias[lane];
#pragma unroll
  for (int s = 0; s < KSPLIT; ++s)
    v += partial[((size_t)s * NT + t) * NE + lane];
  out[L_OFF + (size_t)t * NE + lane] = v;       // approx logit (err ~1e-5 << 1.26)

  // stable rank (lax.top_k order)
  int rank = 0;
  for (int e = 0; e < NE; ++e) {
    float ve = __shfl(v, e);
    rank += (ve > v) || (ve == v && e < lane);
  }

  // rank-neighbor values among ranks 0..8 + boundary value v8
  float up = INFINITY, dn = -INFINITY, v8 = 0.f;
#pragma unroll
  for (int r = 0; r < 9; ++r) {
    unsigned long long b = __ballot(rank == r);
    int src = __ffsll(b) - 1;
    float vr = __shfl(v, src);
    if (rank == r + 1) up = vr;                 // value ranked just above me
    if (rank + 1 == r) dn = vr;                 // value ranked just below me
    if (r == 8) v8 = vr;
  }
  bool flag = (rank <= 8) ? ((up - v < THR) || (v - dn < THR))
                          : (v >= v8 - THR);    // boundary-cluster tail

  // wave compaction: one atomicAdd, packed (t<<6)|e entries
  unsigned long long m = __ballot(flag);
  int n = __popcll(m);
  int base = 0;
  if (lane == 0 && n) base = atomicAdd(cnt, n);
  base = __shfl(base, 0);
  if (flag) {
    int pos = __popcll(m & ((1ull << lane) - 1ull));
    pairs[base + pos] = (t << 6) | lane;
  }
}

// ---- kernel 4: exact round-5-chain recompute, one THREAD per (t,e) pair ----
__global__ __launch_bounds__(256) void k_refine(const float* __restrict__ x,
                                                const float* __restrict__ w,
                                                const float* __restrict__ bias,
                                                const int* __restrict__ cnt,
                                                const int* __restrict__ pairs,
                                                float* __restrict__ out) {
  const int nn = *cnt;
  for (int i = blockIdx.x * 256 + threadIdx.x; i < nn; i += gridDim.x * 256) {
    const int pe = pairs[i];
    const int t = pe >> 6, e = pe & 63;
    const f4* xp = (const f4*)(x + (size_t)t * HD);
    const f4* wp = (const f4*)(w + (size_t)e * HD);
    f4 c = (f4){0.f, 0.f, 0.f, 0.f};
    for (int it = 0; it < HD / 4; it += 8) {
      f4 xv[8], wv[8];
#pragma unroll
      for (int j = 0; j < 8; ++j) { xv[j] = xp[it + j]; wv[j] = wp[it + j]; }
#pragma unroll
      for (int j = 0; j < 8; ++j) {           // EXACT r5 order: k ascending, 4 chains
        c[0] = fmaf(xv[j][0], wv[j][0], c[0]);
        c[1] = fmaf(xv[j][1], wv[j][1], c[1]);
        c[2] = fmaf(xv[j][2], wv[j][2], c[2]);
        c[3] = fmaf(xv[j][3], wv[j][3], c[3]);
      }
    }
    out[L_OFF + (size_t)t * NE + e] = c[0] + c[1] + c[2] + c[3] + bias[e];
  }
}

// ---- kernel 5: zero the fp32 mask region ----
__global__ __launch_bounds__(256) void kz_mask(f4* __restrict__ p, int n4) {
  f4 z = {0.f, 0.f, 0.f, 0.f};
  for (int i = blockIdx.x * 256 + threadIdx.x; i < n4; i += gridDim.x * 256) p[i] = z;
}

// ---- kernel 6: top-8 from logits (rounds 5-15 verbatim selection) ----
__global__ __launch_bounds__(256) void k_topk(float* __restrict__ out) {
  const int lane = threadIdx.x & 63;            // lane == expert
  const int wvi  = threadIdx.x >> 6;
  const int t    = blockIdx.x * 4 + wvi;

  float v = out[L_OFF + (size_t)t * NE + lane];

  int rank = 0;
  for (int e = 0; e < NE; ++e) {
    float ve = __shfl(v, e);
    rank += (ve > v) || (ve == v && e < lane);
  }

  float m0 = v;
#pragma unroll
  for (int o = 32; o; o >>= 1) m0 = fmaxf(m0, __shfl_xor(m0, o));
  float ev = (rank < TOPK) ? expf(v - m0) : 0.f;
  float s = ev;
#pragma unroll
  for (int o = 32; o; o >>= 1) s += __shfl_xor(s, o);

  if (rank < TOPK) {
    out[W_OFF + (size_t)t * TOPK + rank] = ev / s;
    out[I_OFF + (size_t)t * TOPK + rank] = (float)lane;
    out[M_OFF + ((size_t)lane * TOPK + rank) * NT + t] = 1.0f;
  }
}

extern "C" void kernel_launch(void* const* d_in, const int* in_sizes, int n_in,
                              void* d_out, int out_size, void* d_ws, size_t ws_size,
                              hipStream_t stream) {
  const float* x  = (const float*)d_in[0];
  const float* gw = (const float*)d_in[1];
  const float* gb = (const float*)d_in[2];
  float* out = (float*)d_out;

  float* partial = out + M_OFF;
  unsigned short* wh = (unsigned short*)(out + M_OFF + P_FLOATS);
  unsigned short* wl = wh + (size_t)NE * HD;
  int* cnt   = (int*)(out + CNT_OFF);
  int* pairs = (int*)(out + PAIR_OFF);

  k_wconv <<<(NE * HD) / 256, 256, 0, stream>>>(gw, wh, wl, cnt);
  k_gemm  <<<dim3(NT / BM, KSPLIT), 256, 0, stream>>>(x, wh, wl, partial);
  k_reduce<<<NT / 4, 256, 0, stream>>>(partial, gb, out, cnt, pairs);
  k_refine<<<1024, 256, 0, stream>>>(x, gw, gb, cnt, pairs, out);
  kz_mask <<<2048, 256, 0, stream>>>((f4*)(out + M_OFF), (NE * TOPK * NT) / 4);
  k_topk  <<<NT / 4, 256, 0, stream>>>(out);
}

// Round 17
// 292.539 us; speedup vs baseline: 2.1050x; 1.5061x over previous
//
#include <hip/hip_runtime.h>
#include <math.h>

// ---- problem constants ----
#define NT   16384
#define HD   4096
#define NE   64
#define TOPK 8

// ---- MFMA gemm tiling ----
#define BM     64
#define KSPLIT 4
#define KSLICE (HD / KSPLIT)   // 1024

// ---- d_out layout: FLOAT32 elements (proven rounds 5-16) ----
#define L_OFF 0
#define W_OFF (NT * NE)                  // 1048576
#define I_OFF (W_OFF + NT * TOPK)        // 1179648
#define M_OFF (I_OFF + NT * TOPK)        // 1310720 ; mask = 8388608 floats

// scratch inside the mask region (consumed before kz_mask zeroes it):
#define P_FLOATS   (KSPLIT * NT * NE)    // 4194304 (partials)
#define WHL_FLOATS (NE * HD / 2 * 2)     // 262144 floats = 1 MB (wh+wl u16 planes)
#define CNT_OFF    (M_OFF + P_FLOATS + WHL_FLOATS)
#define PAIR_OFF   (CNT_OFF + 1)

#define THR 2.5e-3f                      // refine threshold

typedef __attribute__((ext_vector_type(4))) float  f4;
typedef __attribute__((ext_vector_type(8))) short  short8;
typedef __attribute__((ext_vector_type(8))) __bf16 bf16x8;

__device__ __forceinline__ unsigned short bf16_rne(float f) {
  union { float f; unsigned u; } c; c.f = f;
  unsigned r = c.u + 0x7FFFu + ((c.u >> 16) & 1u);
  return (unsigned short)(r >> 16);
}
__device__ __forceinline__ float bf16_to_f32(unsigned short h) {
  union { unsigned u; float f; } c; c.u = ((unsigned)h) << 16;
  return c.f;
}

// ---- kernel 1: gate_w fp32 -> bf16 hi/lo planes; zero refine counter ----
__global__ __launch_bounds__(256) void k_wconv(const float* __restrict__ w,
                                               unsigned short* __restrict__ wh,
                                               unsigned short* __restrict__ wl,
                                               int* __restrict__ cnt) {
  if (blockIdx.x == 0 && threadIdx.x == 0) *cnt = 0;
  int i = blockIdx.x * 256 + threadIdx.x;       // NE*HD = 262144
  float v = w[i];
  unsigned short h = bf16_rne(v);
  wh[i] = h;
  wl[i] = bf16_rne(v - bf16_to_f32(h));         // v-hi exact (Sterbenz)
}

// ---- kernel 2: split-K MFMA GEMM, hi/lo 3-term; BM=64, 4 blocks/CU ----
__global__ __launch_bounds__(256, 4) void k_gemm(const float* __restrict__ x,
                                                 const unsigned short* __restrict__ wh,
                                                 const unsigned short* __restrict__ wl,
                                                 float* __restrict__ partial) {
  const int lane  = threadIdx.x & 63;
  const int wv    = threadIdx.x >> 6;
  const int tok0  = blockIdx.x * BM;
  const int split = blockIdx.y;
  const int kbase = split * KSLICE;

  const int row15 = lane & 15;
  const int kgrp  = lane >> 4;

  f4 acc[4];
#pragma unroll
  for (int n = 0; n < 4; ++n) acc[n] = (f4){0.f, 0.f, 0.f, 0.f};

  const float* xp = x + (size_t)(tok0 + wv * 16 + row15) * HD + kbase + kgrp * 8;
  const unsigned short* whp = wh + (size_t)row15 * HD + kbase + kgrp * 8;
  const unsigned short* wlp = wl + (size_t)row15 * HD + kbase + kgrp * 8;

#pragma unroll 2
  for (int it = 0; it < KSLICE / 32; ++it) {
    const int ko = it * 32;
    f4 vlo = *(const f4*)(xp + ko);
    f4 vhi = *(const f4*)(xp + ko + 4);
    bf16x8 ah, al;
#pragma unroll
    for (int j = 0; j < 8; ++j) {
      float v = (j < 4) ? vlo[j] : vhi[j - 4];
      __bf16 h = (__bf16)v;
      al[j] = (__bf16)(v - (float)h);
      ah[j] = h;
    }
#pragma unroll
    for (int n = 0; n < 4; ++n) {
      bf16x8 bh = __builtin_bit_cast(bf16x8, *(const short8*)(whp + (size_t)n * 16 * HD + ko));
      bf16x8 bl = __builtin_bit_cast(bf16x8, *(const short8*)(wlp + (size_t)n * 16 * HD + ko));
      acc[n] = __builtin_amdgcn_mfma_f32_16x16x32_bf16(ah, bh, acc[n], 0, 0, 0);
      acc[n] = __builtin_amdgcn_mfma_f32_16x16x32_bf16(al, bh, acc[n], 0, 0, 0);
      acc[n] = __builtin_amdgcn_mfma_f32_16x16x32_bf16(ah, bl, acc[n], 0, 0, 0);
    }
  }

#pragma unroll
  for (int n = 0; n < 4; ++n) {
    int row = tok0 + wv * 16 + (lane >> 4) * 4;
    int col = n * 16 + (lane & 15);
    float* dst = partial + ((size_t)split * NT + row) * NE + col;
#pragma unroll
    for (int i = 0; i < 4; ++i) dst[(size_t)i * NE] = acc[n][i];
  }
}

// ---- kernel 3: reduce -> approx logits; flag tight pairs; compact (t,e) list ----
__global__ __launch_bounds__(256) void k_reduce(const float* __restrict__ partial,
                                                const float* __restrict__ bias,
                                                float* __restrict__ out,
                                                int* __restrict__ cnt,
                                                int* __restrict__ pairs) {
  const int lane = threadIdx.x & 63;            // lane == expert
  const int wvi  = threadIdx.x >> 6;
  const int t    = blockIdx.x * 4 + wvi;

  float v = bias[lane];
#pragma unroll
  for (int s = 0; s < KSPLIT; ++s)
    v += partial[((size_t)s * NT + t) * NE + lane];
  out[L_OFF + (size_t)t * NE + lane] = v;

  int rank = 0;
  for (int e = 0; e < NE; ++e) {
    float ve = __shfl(v, e);
    rank += (ve > v) || (ve == v && e < lane);
  }

  float up = INFINITY, dn = -INFINITY, v8 = 0.f;
#pragma unroll
  for (int r = 0; r < 9; ++r) {
    unsigned long long b = __ballot(rank == r);
    int src = __ffsll(b) - 1;
    float vr = __shfl(v, src);
    if (rank == r + 1) up = vr;
    if (rank + 1 == r) dn = vr;
    if (r == 8) v8 = vr;
  }
  bool flag = (rank <= 8) ? ((up - v < THR) || (v - dn < THR))
                          : (v >= v8 - THR);

  unsigned long long m = __ballot(flag);
  int n = __popcll(m);
  int base = 0;
  if (lane == 0 && n) base = atomicAdd(cnt, n);
  base = __shfl(base, 0);
  if (flag) {
    int pos = __popcll(m & ((1ull << lane) - 1ull));
    pairs[base + pos] = (t << 6) | lane;
  }
}

// ---- kernel 4: exact round-5-chain refine; QUAD per pair (lane j = chain j) ----
// chain j = fmaf over k = j, j+4, ..., j+4092 (ascending); combine ((c0+c1)+c2)+c3+bias
// on lane j==0 of the quad -> bitwise-identical to the proven round-5 logit.
__global__ __launch_bounds__(256) void k_refine(const float* __restrict__ x,
                                                const float* __restrict__ w,
                                                const float* __restrict__ bias,
                                                const int* __restrict__ cnt,
                                                const int* __restrict__ pairs,
                                                float* __restrict__ out) {
  const int nn = *cnt;
  if (nn == 0) return;
  const int lane = threadIdx.x & 63;
  const int wvi  = threadIdx.x >> 6;
  const int quad = lane >> 2;            // 0..15 : pair slot within wave
  const int j    = lane & 3;             // chain id

  for (int base = blockIdx.x * 64; base < nn; base += gridDim.x * 64) {
    const int i  = base + wvi * 16 + quad;
    const int ii = (i < nn) ? i : (nn - 1);
    const int pe = pairs[ii];
    const int t = pe >> 6, e = pe & 63;

    // lane j reads dwords k = m*4 + j (m = 0..1023); quad's 4 lanes coalesce to 16B
    const float* xq = x + (size_t)t * HD + j;
    const float* wq = w + (size_t)e * HD + j;

    float c = 0.f;
    float xa[8], wa[8], xb[8], wb[8];
#pragma unroll
    for (int p = 0; p < 8; ++p) { xa[p] = xq[p * 4];        wa[p] = wq[p * 4]; }
#pragma unroll
    for (int p = 0; p < 8; ++p) { xb[p] = xq[(8 + p) * 4];  wb[p] = wq[(8 + p) * 4]; }

#pragma unroll 1
    for (int b = 0; b < 126; b += 2) {
      // fma batch b (in A), prefetch batch b+2 -> A
#pragma unroll
      for (int p = 0; p < 8; ++p) c = fmaf(xa[p], wa[p], c);
#pragma unroll
      for (int p = 0; p < 8; ++p) { xa[p] = xq[((b + 2) * 8 + p) * 4]; wa[p] = wq[((b + 2) * 8 + p) * 4]; }
      // fma batch b+1 (in B), prefetch batch b+3 -> B
#pragma unroll
      for (int p = 0; p < 8; ++p) c = fmaf(xb[p], wb[p], c);
#pragma unroll
      for (int p = 0; p < 8; ++p) { xb[p] = xq[((b + 3) * 8 + p) * 4]; wb[p] = wq[((b + 3) * 8 + p) * 4]; }
    }
#pragma unroll
    for (int p = 0; p < 8; ++p) c = fmaf(xa[p], wa[p], c);   // batch 126
#pragma unroll
    for (int p = 0; p < 8; ++p) c = fmaf(xb[p], wb[p], c);   // batch 127

    // quad combine in EXACT r5 order
    const int qb = lane & 60;
    float c0 = __shfl(c, qb + 0);
    float c1 = __shfl(c, qb + 1);
    float c2 = __shfl(c, qb + 2);
    float c3 = __shfl(c, qb + 3);
    if (j == 0 && i < nn)
      out[L_OFF + (size_t)t * NE + e] = ((c0 + c1) + c2) + c3 + bias[e];
  }
}

// ---- kernel 5: zero the fp32 mask region ----
__global__ __launch_bounds__(256) void kz_mask(f4* __restrict__ p, int n4) {
  f4 z = {0.f, 0.f, 0.f, 0.f};
  for (int i = blockIdx.x * 256 + threadIdx.x; i < n4; i += gridDim.x * 256) p[i] = z;
}

// ---- kernel 6: top-8 from logits (rounds 5-16 verbatim selection) ----
__global__ __launch_bounds__(256) void k_topk(float* __restrict__ out) {
  const int lane = threadIdx.x & 63;            // lane == expert
  const int wvi  = threadIdx.x >> 6;
  const int t    = blockIdx.x * 4 + wvi;

  float v = out[L_OFF + (size_t)t * NE + lane];

  int rank = 0;
  for (int e = 0; e < NE; ++e) {
    float ve = __shfl(v, e);
    rank += (ve > v) || (ve == v && e < lane);
  }

  float m0 = v;
#pragma unroll
  for (int o = 32; o; o >>= 1) m0 = fmaxf(m0, __shfl_xor(m0, o));
  float ev = (rank < TOPK) ? expf(v - m0) : 0.f;
  float s = ev;
#pragma unroll
  for (int o = 32; o; o >>= 1) s += __shfl_xor(s, o);

  if (rank < TOPK) {
    out[W_OFF + (size_t)t * TOPK + rank] = ev / s;
    out[I_OFF + (size_t)t * TOPK + rank] = (float)lane;
    out[M_OFF + ((size_t)lane * TOPK + rank) * NT + t] = 1.0f;
  }
}

extern "C" void kernel_launch(void* const* d_in, const int* in_sizes, int n_in,
                              void* d_out, int out_size, void* d_ws, size_t ws_size,
                              hipStream_t stream) {
  const float* x  = (const float*)d_in[0];
  const float* gw = (const float*)d_in[1];
  const float* gb = (const float*)d_in[2];
  float* out = (float*)d_out;

  float* partial = out + M_OFF;
  unsigned short* wh = (unsigned short*)(out + M_OFF + P_FLOATS);
  unsigned short* wl = wh + (size_t)NE * HD;
  int* cnt   = (int*)(out + CNT_OFF);
  int* pairs = (int*)(out + PAIR_OFF);

  k_wconv <<<(NE * HD) / 256, 256, 0, stream>>>(gw, wh, wl, cnt);
  k_gemm  <<<dim3(NT / BM, KSPLIT), 256, 0, stream>>>(x, wh, wl, partial);
  k_reduce<<<NT / 4, 256, 0, stream>>>(partial, gb, out, cnt, pairs);
  k_refine<<<256, 256, 0, stream>>>(x, gw, gb, cnt, pairs, out);
  kz_mask <<<2048, 256, 0, stream>>>((f4*)(out + M_OFF), (NE * TOPK * NT) / 4);
  k_topk  <<<NT / 4, 256, 0, stream>>>(out);
}